// Round 1
// baseline (691.946 us; speedup 1.0000x reference)
//
#include <hip/hip_runtime.h>

// GCN: h = emb[x]; two rounds of (GEMM -> gather/scatter with sym-norm -> bias[/relu])
// Strategy: build dst-CSR once (count/scan/fill), then each conv layer is
//   g = (h @ W) * dinv[row]           (dense GEMM, weights in LDS)
//   out[i] = act( dinv[i]*(g[i] + sum_{e: dst=i} g[src_e]) + b )   (gather, no atomics)

static inline int cdiv(int a, int b){ return (a + b - 1) / b; }

__global__ void k_zero_i32(int* __restrict__ p, int n){
    int i = blockIdx.x * blockDim.x + threadIdx.x;
    if (i < n) p[i] = 0;
}

__global__ void k_count(const int* __restrict__ dst, int E, int* __restrict__ ecount){
    int e = blockIdx.x * blockDim.x + threadIdx.x;
    if (e < E) atomicAdd(&ecount[dst[e]], 1);
}

__global__ void k_dinv(const int* __restrict__ ecount, float* __restrict__ dinv, int n){
    int i = blockIdx.x * blockDim.x + threadIdx.x;
    if (i < n) dinv[i] = rsqrtf((float)ecount[i] + 1.0f);  // +1 self-loop
}

// --- 3-kernel exclusive scan over ecount[0..n) -> offsets ---
__global__ void k_scanA(const int* __restrict__ ecount, int n, int* __restrict__ bsum){
    __shared__ int s[256];
    int t = threadIdx.x;
    int i = blockIdx.x * 256 + t;
    s[t] = (i < n) ? ecount[i] : 0;
    __syncthreads();
    for (int d = 128; d > 0; d >>= 1){
        if (t < d) s[t] += s[t + d];
        __syncthreads();
    }
    if (t == 0) bsum[blockIdx.x] = s[0];
}

__global__ void k_scanB(int* __restrict__ bsum, int nb){
    // nb <= 256 (N=50000 -> 196 blocks). Serial scan in LDS.
    __shared__ int s[256];
    int t = threadIdx.x;
    s[t] = (t < nb) ? bsum[t] : 0;
    __syncthreads();
    if (t == 0){
        int run = 0;
        for (int b = 0; b < nb; b++){ int v = s[b]; s[b] = run; run += v; }
    }
    __syncthreads();
    if (t < nb) bsum[t] = s[t];
}

__global__ void k_scanC(const int* __restrict__ ecount, int n, const int* __restrict__ bsum,
                        int* __restrict__ offsets, int* __restrict__ cursor){
    __shared__ int s[256];
    int t = threadIdx.x;
    int i = blockIdx.x * 256 + t;
    int v = (i < n) ? ecount[i] : 0;
    s[t] = v;
    __syncthreads();
    for (int d = 1; d < 256; d <<= 1){           // Hillis-Steele inclusive
        int x = (t >= d) ? s[t - d] : 0;
        __syncthreads();
        s[t] += x;
        __syncthreads();
    }
    if (i < n){
        int off = bsum[blockIdx.x] + s[t] - v;   // exclusive
        offsets[i] = off;
        cursor[i]  = off;
    }
}

__global__ void k_fill(const int* __restrict__ src, const int* __restrict__ dst, int E,
                       int* __restrict__ cursor, int* __restrict__ csr_src){
    int e = blockIdx.x * blockDim.x + threadIdx.x;
    if (e < E){
        int d = dst[e];
        int pos = atomicAdd(&cursor[d], 1);
        csr_src[pos] = src[e];
    }
}

// g1[i][j] = (sum_k emb[x[i]][k] * W1[k][j]) * dinv[i]   ; K=32, 128 cols
__global__ __launch_bounds__(128) void k_gemm1(const float* __restrict__ emb, const int* __restrict__ x,
                                               const float* __restrict__ W1, const float* __restrict__ dinv,
                                               float* __restrict__ g1, int n){
    __shared__ float w[32 * 128];   // 16 KB
    for (int i = threadIdx.x; i < 32 * 128; i += 128) w[i] = W1[i];
    __syncthreads();
    int j = threadIdx.x;
    for (int row = blockIdx.x; row < n; row += gridDim.x){
        int xi = x[row];
        const float* er = emb + (size_t)xi * 32;
        float s = 0.f;
        #pragma unroll
        for (int k = 0; k < 32; k++) s += er[k] * w[k * 128 + j];   // er[k]: wave-broadcast
        g1[(size_t)row * 128 + j] = s * dinv[row];
    }
}

// Per-node gather-aggregate + fused epilogue. One 128-thread block per node.
__global__ __launch_bounds__(128) void k_agg(const float* __restrict__ g, const int* __restrict__ offsets,
                                             const int* __restrict__ ecount, const int* __restrict__ csr,
                                             const float* __restrict__ dinv, const float* __restrict__ bias,
                                             float* __restrict__ outbuf, int n, int do_relu){
    int i = blockIdx.x;
    int j = threadIdx.x;
    int off = offsets[i];
    int cnt = ecount[i];
    float s = g[(size_t)i * 128 + j];            // self-loop term (g already * dinv[src])
    for (int e = 0; e < cnt; e++){
        int src = csr[off + e];                  // uniform -> one cache line
        s += g[(size_t)src * 128 + j];           // coalesced 512B row read
    }
    float v = dinv[i] * s + bias[j];
    if (do_relu) v = fmaxf(v, 0.f);
    outbuf[(size_t)i * 128 + j] = v;
}

// g2[i][:] = (h[i][:] @ W2) * dinv[i]  ; 128x128 W2 in LDS, float4 columns,
// 8 rows per 256-thread block iteration (32 lanes x 4 cols per row).
__global__ __launch_bounds__(256) void k_gemm2(const float* __restrict__ h, const float* __restrict__ W2,
                                               const float* __restrict__ dinv, float* __restrict__ g2, int n){
    __shared__ float w[128 * 128];   // 64 KB (static LDS cap)
    for (int i = threadIdx.x; i < 128 * 128; i += 256) w[i] = W2[i];
    __syncthreads();
    int r  = threadIdx.x >> 5;         // local row 0..7
    int c4 = (threadIdx.x & 31) * 4;   // column base
    for (int base = blockIdx.x * 8; base < n; base += gridDim.x * 8){
        int row = base + r;
        if (row < n){
            const float* hr = h + (size_t)row * 128;
            float4 acc = make_float4(0.f, 0.f, 0.f, 0.f);
            for (int k = 0; k < 128; k++){
                float hv = hr[k];                              // wave-broadcast L1 hit
                float4 wv = *(const float4*)&w[k * 128 + c4];  // ds_read_b128, conflict-free
                acc.x += hv * wv.x; acc.y += hv * wv.y;
                acc.z += hv * wv.z; acc.w += hv * wv.w;
            }
            float dv = dinv[row];
            acc.x *= dv; acc.y *= dv; acc.z *= dv; acc.w *= dv;
            *(float4*)&g2[(size_t)row * 128 + c4] = acc;
        }
    }
}

extern "C" void kernel_launch(void* const* d_in, const int* in_sizes, int n_in,
                              void* d_out, int out_size, void* d_ws, size_t ws_size,
                              hipStream_t stream){
    const int*   x    = (const int*)d_in[0];
    const int*   ei   = (const int*)d_in[1];
    const float* emb  = (const float*)d_in[2];
    const float* W1   = (const float*)d_in[3];
    const float* b1   = (const float*)d_in[4];
    const float* W2   = (const float*)d_in[5];
    const float* b2   = (const float*)d_in[6];
    const int N = in_sizes[0];
    const int E = in_sizes[1] / 2;
    const int* srcv = ei;        // edge_index[0]
    const int* dstv = ei + E;    // edge_index[1]
    float* out = (float*)d_out;

    // workspace carve (aligned to 256B); total ~59 MB
    char* p = (char*)d_ws;
    auto alloc = [&](size_t bytes) -> char* {
        char* r = p; p += (bytes + 255) & ~(size_t)255; return r;
    };
    int nb = cdiv(N, 256);
    int*   ecount  = (int*)  alloc((size_t)N * 4);
    int*   offsets = (int*)  alloc((size_t)N * 4);
    int*   cursor  = (int*)  alloc((size_t)N * 4);
    int*   bsum    = (int*)  alloc((size_t)nb * 4);
    float* dinv    = (float*)alloc((size_t)N * 4);
    int*   csr     = (int*)  alloc((size_t)E * 4);
    float* bufA    = (float*)alloc((size_t)N * 128 * 4);  // g1 then g2
    float* bufB    = (float*)alloc((size_t)N * 128 * 4);  // h (post-relu)
    (void)ws_size; (void)n_in; (void)out_size;

    // --- CSR build ---
    k_zero_i32<<<cdiv(N, 256), 256, 0, stream>>>(ecount, N);
    k_count   <<<cdiv(E, 256), 256, 0, stream>>>(dstv, E, ecount);
    k_dinv    <<<cdiv(N, 256), 256, 0, stream>>>(ecount, dinv, N);
    k_scanA   <<<nb, 256, 0, stream>>>(ecount, N, bsum);
    k_scanB   <<<1, 256, 0, stream>>>(bsum, nb);
    k_scanC   <<<nb, 256, 0, stream>>>(ecount, N, bsum, offsets, cursor);
    k_fill    <<<cdiv(E, 256), 256, 0, stream>>>(srcv, dstv, E, cursor, csr);

    // --- layer 1 ---
    k_gemm1<<<1024, 128, 0, stream>>>(emb, x, W1, dinv, bufA, N);
    k_agg  <<<N, 128, 0, stream>>>(bufA, offsets, ecount, csr, dinv, b1, bufB, N, 1);

    // --- layer 2 ---
    k_gemm2<<<1024, 256, 0, stream>>>(bufB, W2, dinv, bufA, N);
    k_agg  <<<N, 128, 0, stream>>>(bufA, offsets, ecount, csr, dinv, b2, out, N, 0);
}

// Round 2
// 499.913 us; speedup vs baseline: 1.3841x; 1.3841x over previous
//
#include <hip/hip_runtime.h>

// GCN restructured: agg-before-GEMM on both layers (A(hW) = (Ah)W).
//   es  = dinv[i] * emb[x[i]]                       (N x 32)
//   a1  = dinv[i] * (es[i] + sum_{e:dst=i} es[src]) (N x 32 gather, 128 B/edge)
//   hs  = dinv[i] * relu(a1 @ W1 + b1)              (N x 128)
//   a2  = dinv[i] * (hs[i] + sum hs[src])           (N x 128 gather, 512 B/edge)
//   out = a2 @ W2 + b2
// CSR (dst-sorted) built once per call: count -> scan -> fill. No float atomics.

static inline int cdiv(int a, int b){ return (a + b - 1) / b; }

__device__ __forceinline__ void f4acc(float4& a, const float4 b){
    a.x += b.x; a.y += b.y; a.z += b.z; a.w += b.w;
}

__global__ void k_zero_i32(int* __restrict__ p, int n){
    int i = blockIdx.x * blockDim.x + threadIdx.x;
    if (i < n) p[i] = 0;
}

__global__ void k_count(const int* __restrict__ dst, int E, int* __restrict__ ecount){
    int e = blockIdx.x * blockDim.x + threadIdx.x;
    if (e < E) atomicAdd(&ecount[dst[e]], 1);
}

__global__ void k_dinv(const int* __restrict__ ecount, float* __restrict__ dinv, int n){
    int i = blockIdx.x * blockDim.x + threadIdx.x;
    if (i < n) dinv[i] = rsqrtf((float)ecount[i] + 1.0f);  // +1 self-loop
}

__global__ void k_scanA(const int* __restrict__ ecount, int n, int* __restrict__ bsum){
    __shared__ int s[256];
    int t = threadIdx.x;
    int i = blockIdx.x * 256 + t;
    s[t] = (i < n) ? ecount[i] : 0;
    __syncthreads();
    for (int d = 128; d > 0; d >>= 1){
        if (t < d) s[t] += s[t + d];
        __syncthreads();
    }
    if (t == 0) bsum[blockIdx.x] = s[0];
}

__global__ void k_scanB(int* __restrict__ bsum, int nb){
    __shared__ int s[256];
    int t = threadIdx.x;
    s[t] = (t < nb) ? bsum[t] : 0;
    __syncthreads();
    if (t == 0){
        int run = 0;
        for (int b = 0; b < nb; b++){ int v = s[b]; s[b] = run; run += v; }
    }
    __syncthreads();
    if (t < nb) bsum[t] = s[t];
}

__global__ void k_scanC(const int* __restrict__ ecount, int n, const int* __restrict__ bsum,
                        int* __restrict__ offsets, int* __restrict__ cursor){
    __shared__ int s[256];
    int t = threadIdx.x;
    int i = blockIdx.x * 256 + t;
    int v = (i < n) ? ecount[i] : 0;
    s[t] = v;
    __syncthreads();
    for (int d = 1; d < 256; d <<= 1){
        int x = (t >= d) ? s[t - d] : 0;
        __syncthreads();
        s[t] += x;
        __syncthreads();
    }
    if (i < n){
        int off = bsum[blockIdx.x] + s[t] - v;
        offsets[i] = off;
        cursor[i]  = off;
    }
}

__global__ void k_fill(const int* __restrict__ src, const int* __restrict__ dst, int E,
                       int* __restrict__ cursor, int* __restrict__ csr_src){
    int e = blockIdx.x * blockDim.x + threadIdx.x;
    if (e < E){
        int d = dst[e];
        int pos = atomicAdd(&cursor[d], 1);
        csr_src[pos] = src[e];
    }
}

// es[i][c] = emb[x[i]][c] * dinv[i]
__global__ void k_scale(const float* __restrict__ emb, const int* __restrict__ x,
                        const float* __restrict__ dinv, float* __restrict__ es, int n){
    int idx = blockIdx.x * blockDim.x + threadIdx.x;
    if (idx >= n * 32) return;
    int i = idx >> 5;
    int c = idx & 31;
    es[idx] = emb[(size_t)x[i] * 32 + c] * dinv[i];
}

// a1[i] = dinv[i] * (es[i] + sum es[src]) ; 32 lanes/node, scalar float, unroll 4.
__global__ __launch_bounds__(256) void k_agg32(const float* __restrict__ es,
        const int* __restrict__ offsets, const int* __restrict__ ecount,
        const int* __restrict__ csr, const float* __restrict__ dinv,
        float* __restrict__ a1, int n){
    int node = blockIdx.x * 8 + (threadIdx.x >> 5);
    int lane = threadIdx.x & 31;
    if (node >= n) return;
    int off = offsets[node], cnt = ecount[node];
    float s0 = es[(size_t)node * 32 + lane];   // self-loop term
    float s1 = 0.f;
    int e = 0;
    for (; e + 4 <= cnt; e += 4){
        int i0 = csr[off + e + 0], i1 = csr[off + e + 1];
        int i2 = csr[off + e + 2], i3 = csr[off + e + 3];
        float v0 = es[(size_t)i0 * 32 + lane];
        float v1 = es[(size_t)i1 * 32 + lane];
        float v2 = es[(size_t)i2 * 32 + lane];
        float v3 = es[(size_t)i3 * 32 + lane];
        s0 += v0 + v2;
        s1 += v1 + v3;
    }
    for (; e < cnt; e++) s0 += es[(size_t)csr[off + e] * 32 + lane];
    a1[(size_t)node * 32 + lane] = dinv[node] * (s0 + s1);
}

// hs[i] = dinv[i] * relu(a1[i] @ W1 + b1) ; W1 in LDS (16 KB), K=32 fully unrolled.
__global__ __launch_bounds__(256) void k_mlp1(const float* __restrict__ a1,
        const float* __restrict__ W1, const float* __restrict__ b1,
        const float* __restrict__ dinv, float* __restrict__ hs, int n){
    __shared__ float w[32 * 128];
    for (int i = threadIdx.x; i < 32 * 128; i += 256) w[i] = W1[i];
    __syncthreads();
    int c4  = (threadIdx.x & 31) * 4;
    int row = blockIdx.x * 8 + (threadIdx.x >> 5);
    if (row >= n) return;
    const float4* ar = (const float4*)(a1 + (size_t)row * 32);
    float4 acc = *(const float4*)(b1 + c4);
    #pragma unroll
    for (int k4 = 0; k4 < 8; k4++){
        float4 av = ar[k4];
        float4 w0 = *(const float4*)&w[(k4 * 4 + 0) * 128 + c4];
        float4 w1 = *(const float4*)&w[(k4 * 4 + 1) * 128 + c4];
        float4 w2 = *(const float4*)&w[(k4 * 4 + 2) * 128 + c4];
        float4 w3 = *(const float4*)&w[(k4 * 4 + 3) * 128 + c4];
        acc.x += av.x * w0.x + av.y * w1.x + av.z * w2.x + av.w * w3.x;
        acc.y += av.x * w0.y + av.y * w1.y + av.z * w2.y + av.w * w3.y;
        acc.z += av.x * w0.z + av.y * w1.z + av.z * w2.z + av.w * w3.z;
        acc.w += av.x * w0.w + av.y * w1.w + av.z * w2.w + av.w * w3.w;
    }
    float dv = dinv[row];
    acc.x = dv * fmaxf(acc.x, 0.f);
    acc.y = dv * fmaxf(acc.y, 0.f);
    acc.z = dv * fmaxf(acc.z, 0.f);
    acc.w = dv * fmaxf(acc.w, 0.f);
    *(float4*)(hs + (size_t)row * 128 + c4) = acc;
}

// a2[i] = dinv[i] * (hs[i] + sum hs[src]) ; 32 lanes/node, float4/lane, unroll 4.
__global__ __launch_bounds__(256) void k_agg128(const float* __restrict__ hs,
        const int* __restrict__ offsets, const int* __restrict__ ecount,
        const int* __restrict__ csr, const float* __restrict__ dinv,
        float* __restrict__ a2, int n){
    int node = blockIdx.x * 8 + (threadIdx.x >> 5);
    int lane = threadIdx.x & 31;
    if (node >= n) return;
    int off = offsets[node], cnt = ecount[node];
    int c4 = lane * 4;
    float4 s0 = *(const float4*)(hs + (size_t)node * 128 + c4);  // self-loop
    float4 s1 = make_float4(0.f, 0.f, 0.f, 0.f);
    int e = 0;
    for (; e + 4 <= cnt; e += 4){
        int i0 = csr[off + e + 0], i1 = csr[off + e + 1];
        int i2 = csr[off + e + 2], i3 = csr[off + e + 3];
        float4 v0 = *(const float4*)(hs + (size_t)i0 * 128 + c4);
        float4 v1 = *(const float4*)(hs + (size_t)i1 * 128 + c4);
        float4 v2 = *(const float4*)(hs + (size_t)i2 * 128 + c4);
        float4 v3 = *(const float4*)(hs + (size_t)i3 * 128 + c4);
        f4acc(s0, v0); f4acc(s1, v1); f4acc(s0, v2); f4acc(s1, v3);
    }
    for (; e < cnt; e++){
        float4 v = *(const float4*)(hs + (size_t)csr[off + e] * 128 + c4);
        f4acc(s0, v);
    }
    float dv = dinv[node];
    float4 r;
    r.x = dv * (s0.x + s1.x); r.y = dv * (s0.y + s1.y);
    r.z = dv * (s0.z + s1.z); r.w = dv * (s0.w + s1.w);
    *(float4*)(a2 + (size_t)node * 128 + c4) = r;
}

// out[i] = a2[i] @ W2 + b2 ; W2 in LDS (64 KB), 4 rows x 4 cols per thread.
#define MLP2_STEP(KK, COMP) {                                        \
    float4 wv = *(const float4*)&w[(k + KK) * 128 + c4];             \
    acc0.x += a0.COMP * wv.x; acc0.y += a0.COMP * wv.y;              \
    acc0.z += a0.COMP * wv.z; acc0.w += a0.COMP * wv.w;              \
    acc1.x += a1v.COMP * wv.x; acc1.y += a1v.COMP * wv.y;            \
    acc1.z += a1v.COMP * wv.z; acc1.w += a1v.COMP * wv.w;            \
    acc2.x += a2v.COMP * wv.x; acc2.y += a2v.COMP * wv.y;            \
    acc2.z += a2v.COMP * wv.z; acc2.w += a2v.COMP * wv.w;            \
    acc3.x += a3v.COMP * wv.x; acc3.y += a3v.COMP * wv.y;            \
    acc3.z += a3v.COMP * wv.z; acc3.w += a3v.COMP * wv.w; }

__global__ __launch_bounds__(256) void k_mlp2(const float* __restrict__ a2,
        const float* __restrict__ W2, const float* __restrict__ b2,
        float* __restrict__ out, int n){
    __shared__ float w[128 * 128];   // 64 KB
    for (int i = threadIdx.x; i < 128 * 128; i += 256) w[i] = W2[i];
    __syncthreads();
    int c4 = (threadIdx.x & 31) * 4;
    int r0 = blockIdx.x * 32 + (threadIdx.x >> 5) * 4;
    float4 bias = *(const float4*)(b2 + c4);
    float4 acc0 = bias, acc1 = bias, acc2 = bias, acc3 = bias;
    const float* h0 = a2 + (size_t)(r0 + 0) * 128;
    const float* h1 = a2 + (size_t)(r0 + 1) * 128;
    const float* h2 = a2 + (size_t)(r0 + 2) * 128;
    const float* h3 = a2 + (size_t)(r0 + 3) * 128;
    bool g0 = r0 + 0 < n, g1 = r0 + 1 < n, g2 = r0 + 2 < n, g3 = r0 + 3 < n;
    const float4 z = make_float4(0.f, 0.f, 0.f, 0.f);
    for (int k = 0; k < 128; k += 4){
        float4 a0  = g0 ? *(const float4*)(h0 + k) : z;
        float4 a1v = g1 ? *(const float4*)(h1 + k) : z;
        float4 a2v = g2 ? *(const float4*)(h2 + k) : z;
        float4 a3v = g3 ? *(const float4*)(h3 + k) : z;
        MLP2_STEP(0, x)
        MLP2_STEP(1, y)
        MLP2_STEP(2, z)
        MLP2_STEP(3, w)
    }
    if (g0) *(float4*)(out + (size_t)(r0 + 0) * 128 + c4) = acc0;
    if (g1) *(float4*)(out + (size_t)(r0 + 1) * 128 + c4) = acc1;
    if (g2) *(float4*)(out + (size_t)(r0 + 2) * 128 + c4) = acc2;
    if (g3) *(float4*)(out + (size_t)(r0 + 3) * 128 + c4) = acc3;
}

extern "C" void kernel_launch(void* const* d_in, const int* in_sizes, int n_in,
                              void* d_out, int out_size, void* d_ws, size_t ws_size,
                              hipStream_t stream){
    const int*   x    = (const int*)d_in[0];
    const int*   ei   = (const int*)d_in[1];
    const float* emb  = (const float*)d_in[2];
    const float* W1   = (const float*)d_in[3];
    const float* b1   = (const float*)d_in[4];
    const float* W2   = (const float*)d_in[5];
    const float* b2   = (const float*)d_in[6];
    const int N = in_sizes[0];
    const int E = in_sizes[1] / 2;
    const int* srcv = ei;
    const int* dstv = ei + E;
    float* out = (float*)d_out;

    char* p = (char*)d_ws;
    auto alloc = [&](size_t bytes) -> char* {
        char* r = p; p += (bytes + 255) & ~(size_t)255; return r;
    };
    int nb = cdiv(N, 256);
    int*   ecount  = (int*)  alloc((size_t)N * 4);
    int*   offsets = (int*)  alloc((size_t)N * 4);
    int*   cursor  = (int*)  alloc((size_t)N * 4);
    int*   bsum    = (int*)  alloc((size_t)nb * 4);
    float* dinv    = (float*)alloc((size_t)N * 4);
    int*   csr     = (int*)  alloc((size_t)E * 4);
    float* es      = (float*)alloc((size_t)N * 32 * 4);
    float* a1      = (float*)alloc((size_t)N * 32 * 4);
    float* hs      = (float*)alloc((size_t)N * 128 * 4);
    float* a2      = (float*)alloc((size_t)N * 128 * 4);
    (void)ws_size; (void)n_in; (void)out_size;

    // --- CSR build ---
    k_zero_i32<<<cdiv(N, 256), 256, 0, stream>>>(ecount, N);
    k_count   <<<cdiv(E, 256), 256, 0, stream>>>(dstv, E, ecount);
    k_dinv    <<<cdiv(N, 256), 256, 0, stream>>>(ecount, dinv, N);
    k_scanA   <<<nb, 256, 0, stream>>>(ecount, N, bsum);
    k_scanB   <<<1, 256, 0, stream>>>(bsum, nb);
    k_scanC   <<<nb, 256, 0, stream>>>(ecount, N, bsum, offsets, cursor);
    k_fill    <<<cdiv(E, 256), 256, 0, stream>>>(srcv, dstv, E, cursor, csr);

    // --- layer 1: scale -> agg(32) -> GEMM+relu (+dinv pre-scale for layer 2) ---
    k_scale <<<cdiv(N * 32, 256), 256, 0, stream>>>(emb, x, dinv, es, N);
    k_agg32 <<<cdiv(N, 8), 256, 0, stream>>>(es, offsets, ecount, csr, dinv, a1, N);
    k_mlp1  <<<cdiv(N, 8), 256, 0, stream>>>(a1, W1, b1, dinv, hs, N);

    // --- layer 2: agg(128) -> GEMM+bias -> out ---
    k_agg128<<<cdiv(N, 8), 256, 0, stream>>>(hs, offsets, ecount, csr, dinv, a2, N);
    k_mlp2  <<<cdiv(N, 32), 256, 0, stream>>>(a2, W2, b2, out, N);
}

// Round 3
// 467.135 us; speedup vs baseline: 1.4813x; 1.0702x over previous
//
#include <hip/hip_runtime.h>

// GCN: agg-before-GEMM on both layers (A(hW) = (Ah)W).
//   es  = dinv[i] * emb[x[i]]                       (N x 32)
//   a1  = dinv[i] * (es[i] + sum_{e:dst=i} es[src]) (N x 32 gather)
//   hs  = dinv[i] * relu(a1 @ W1 + b1)              (N x 128)
//   a2  = dinv[i] * (hs[i] + sum hs[src])           (N x 128 gather)
//   out = a2 @ W2 + b2
// CSR build (count/scan/fill) uses dst-range partitioning with partition =
// blockIdx%8 (XCD-aligned) so scattered atomics/writes stay in one XCD's L2
// and cache lines fill completely before writeback (R2: WRITE_SIZE was E*64B).

static inline int cdiv(int a, int b){ return (a + b - 1) / b; }

__device__ __forceinline__ void f4acc(float4& a, const float4 b){
    a.x += b.x; a.y += b.y; a.z += b.z; a.w += b.w;
}

__global__ void k_zero_i32(int* __restrict__ p, int n){
    int i = blockIdx.x * blockDim.x + threadIdx.x;
    if (i < n) p[i] = 0;
}

// Partitioned count: partition = blockIdx%8 handles dst in [lo,hi).
__global__ __launch_bounds__(256) void k_count(const int* __restrict__ dst, int E,
                                               int* __restrict__ ecount, int npp){
    int part = blockIdx.x & 7;
    int sub  = blockIdx.x >> 3;
    int nsub = gridDim.x >> 3;
    int lo = part * npp, hi = lo + npp;
    for (int e = sub * 256 + threadIdx.x; e < E; e += nsub * 256){
        int d = dst[e];
        if (d >= lo && d < hi) atomicAdd(&ecount[d], 1);
    }
}

__global__ void k_dinv(const int* __restrict__ ecount, float* __restrict__ dinv, int n){
    int i = blockIdx.x * blockDim.x + threadIdx.x;
    if (i < n) dinv[i] = rsqrtf((float)ecount[i] + 1.0f);  // +1 self-loop
}

__global__ void k_scanA(const int* __restrict__ ecount, int n, int* __restrict__ bsum){
    __shared__ int s[256];
    int t = threadIdx.x;
    int i = blockIdx.x * 256 + t;
    s[t] = (i < n) ? ecount[i] : 0;
    __syncthreads();
    for (int d = 128; d > 0; d >>= 1){
        if (t < d) s[t] += s[t + d];
        __syncthreads();
    }
    if (t == 0) bsum[blockIdx.x] = s[0];
}

__global__ void k_scanB(int* __restrict__ bsum, int nb){
    __shared__ int s[256];
    int t = threadIdx.x;
    s[t] = (t < nb) ? bsum[t] : 0;
    __syncthreads();
    if (t == 0){
        int run = 0;
        for (int b = 0; b < nb; b++){ int v = s[b]; s[b] = run; run += v; }
    }
    __syncthreads();
    if (t < nb) bsum[t] = s[t];
}

__global__ void k_scanC(const int* __restrict__ ecount, int n, const int* __restrict__ bsum,
                        int* __restrict__ offsets, int* __restrict__ cursor){
    __shared__ int s[256];
    int t = threadIdx.x;
    int i = blockIdx.x * 256 + t;
    int v = (i < n) ? ecount[i] : 0;
    s[t] = v;
    __syncthreads();
    for (int d = 1; d < 256; d <<= 1){
        int x = (t >= d) ? s[t - d] : 0;
        __syncthreads();
        s[t] += x;
        __syncthreads();
    }
    if (i < n){
        int off = bsum[blockIdx.x] + s[t] - v;
        offsets[i] = off;
        cursor[i]  = off;
    }
}

// Partitioned fill: same partition scheme as k_count.
__global__ __launch_bounds__(256) void k_fill(const int* __restrict__ src,
        const int* __restrict__ dst, int E, int* __restrict__ cursor,
        int* __restrict__ csr_src, int npp){
    int part = blockIdx.x & 7;
    int sub  = blockIdx.x >> 3;
    int nsub = gridDim.x >> 3;
    int lo = part * npp, hi = lo + npp;
    for (int e = sub * 256 + threadIdx.x; e < E; e += nsub * 256){
        int d = dst[e];
        if (d >= lo && d < hi){
            int pos = atomicAdd(&cursor[d], 1);
            csr_src[pos] = src[e];
        }
    }
}

// es[i][c] = emb[x[i]][c] * dinv[i]
__global__ void k_scale(const float* __restrict__ emb, const int* __restrict__ x,
                        const float* __restrict__ dinv, float* __restrict__ es, int n){
    int idx = blockIdx.x * blockDim.x + threadIdx.x;
    if (idx >= n * 32) return;
    int i = idx >> 5;
    int c = idx & 31;
    es[idx] = emb[(size_t)x[i] * 32 + c] * dinv[i];
}

// a1[i] = dinv[i] * (es[i] + sum es[src]) ; 32 lanes/node, unroll 4.
__global__ __launch_bounds__(256) void k_agg32(const float* __restrict__ es,
        const int* __restrict__ offsets, const int* __restrict__ ecount,
        const int* __restrict__ csr, const float* __restrict__ dinv,
        float* __restrict__ a1, int n){
    int node = blockIdx.x * 8 + (threadIdx.x >> 5);
    int lane = threadIdx.x & 31;
    if (node >= n) return;
    int off = offsets[node], cnt = ecount[node];
    float s0 = es[(size_t)node * 32 + lane];   // self-loop term
    float s1 = 0.f;
    int e = 0;
    for (; e + 4 <= cnt; e += 4){
        int i0 = csr[off + e + 0], i1 = csr[off + e + 1];
        int i2 = csr[off + e + 2], i3 = csr[off + e + 3];
        float v0 = es[(size_t)i0 * 32 + lane];
        float v1 = es[(size_t)i1 * 32 + lane];
        float v2 = es[(size_t)i2 * 32 + lane];
        float v3 = es[(size_t)i3 * 32 + lane];
        s0 += v0 + v2;
        s1 += v1 + v3;
    }
    for (; e < cnt; e++) s0 += es[(size_t)csr[off + e] * 32 + lane];
    a1[(size_t)node * 32 + lane] = dinv[node] * (s0 + s1);
}

// hs[i] = dinv[i] * relu(a1[i] @ W1 + b1) ; W1 in LDS (16 KB), K=32 unrolled.
__global__ __launch_bounds__(256) void k_mlp1(const float* __restrict__ a1,
        const float* __restrict__ W1, const float* __restrict__ b1,
        const float* __restrict__ dinv, float* __restrict__ hs, int n){
    __shared__ float w[32 * 128];
    for (int i = threadIdx.x; i < 32 * 128; i += 256) w[i] = W1[i];
    __syncthreads();
    int c4  = (threadIdx.x & 31) * 4;
    int row = blockIdx.x * 8 + (threadIdx.x >> 5);
    if (row >= n) return;
    const float4* ar = (const float4*)(a1 + (size_t)row * 32);
    float4 acc = *(const float4*)(b1 + c4);
    #pragma unroll
    for (int k4 = 0; k4 < 8; k4++){
        float4 av = ar[k4];
        float4 w0 = *(const float4*)&w[(k4 * 4 + 0) * 128 + c4];
        float4 w1 = *(const float4*)&w[(k4 * 4 + 1) * 128 + c4];
        float4 w2 = *(const float4*)&w[(k4 * 4 + 2) * 128 + c4];
        float4 w3 = *(const float4*)&w[(k4 * 4 + 3) * 128 + c4];
        acc.x += av.x * w0.x + av.y * w1.x + av.z * w2.x + av.w * w3.x;
        acc.y += av.x * w0.y + av.y * w1.y + av.z * w2.y + av.w * w3.y;
        acc.z += av.x * w0.z + av.y * w1.z + av.z * w2.z + av.w * w3.z;
        acc.w += av.x * w0.w + av.y * w1.w + av.z * w2.w + av.w * w3.w;
    }
    float dv = dinv[row];
    acc.x = dv * fmaxf(acc.x, 0.f);
    acc.y = dv * fmaxf(acc.y, 0.f);
    acc.z = dv * fmaxf(acc.z, 0.f);
    acc.w = dv * fmaxf(acc.w, 0.f);
    *(float4*)(hs + (size_t)row * 128 + c4) = acc;
}

// a2[i] = dinv[i] * (hs[i] + sum hs[src]) ; 32 lanes/node, float4/lane, unroll 4.
__global__ __launch_bounds__(256) void k_agg128(const float* __restrict__ hs,
        const int* __restrict__ offsets, const int* __restrict__ ecount,
        const int* __restrict__ csr, const float* __restrict__ dinv,
        float* __restrict__ a2, int n){
    int node = blockIdx.x * 8 + (threadIdx.x >> 5);
    int lane = threadIdx.x & 31;
    if (node >= n) return;
    int off = offsets[node], cnt = ecount[node];
    int c4 = lane * 4;
    float4 s0 = *(const float4*)(hs + (size_t)node * 128 + c4);  // self-loop
    float4 s1 = make_float4(0.f, 0.f, 0.f, 0.f);
    int e = 0;
    for (; e + 4 <= cnt; e += 4){
        int i0 = csr[off + e + 0], i1 = csr[off + e + 1];
        int i2 = csr[off + e + 2], i3 = csr[off + e + 3];
        float4 v0 = *(const float4*)(hs + (size_t)i0 * 128 + c4);
        float4 v1 = *(const float4*)(hs + (size_t)i1 * 128 + c4);
        float4 v2 = *(const float4*)(hs + (size_t)i2 * 128 + c4);
        float4 v3 = *(const float4*)(hs + (size_t)i3 * 128 + c4);
        f4acc(s0, v0); f4acc(s1, v1); f4acc(s0, v2); f4acc(s1, v3);
    }
    for (; e < cnt; e++){
        float4 v = *(const float4*)(hs + (size_t)csr[off + e] * 128 + c4);
        f4acc(s0, v);
    }
    float dv = dinv[node];
    float4 r;
    r.x = dv * (s0.x + s1.x); r.y = dv * (s0.y + s1.y);
    r.z = dv * (s0.z + s1.z); r.w = dv * (s0.w + s1.w);
    *(float4*)(a2 + (size_t)node * 128 + c4) = r;
}

// out[i] = a2[i] @ W2 + b2 ; W2 in LDS (64 KB), 4 rows x 4 cols per thread.
#define MLP2_STEP(KK, COMP) {                                        \
    float4 wv = *(const float4*)&w[(k + KK) * 128 + c4];             \
    acc0.x += a0.COMP * wv.x; acc0.y += a0.COMP * wv.y;              \
    acc0.z += a0.COMP * wv.z; acc0.w += a0.COMP * wv.w;              \
    acc1.x += a1v.COMP * wv.x; acc1.y += a1v.COMP * wv.y;            \
    acc1.z += a1v.COMP * wv.z; acc1.w += a1v.COMP * wv.w;            \
    acc2.x += a2v.COMP * wv.x; acc2.y += a2v.COMP * wv.y;            \
    acc2.z += a2v.COMP * wv.z; acc2.w += a2v.COMP * wv.w;            \
    acc3.x += a3v.COMP * wv.x; acc3.y += a3v.COMP * wv.y;            \
    acc3.z += a3v.COMP * wv.z; acc3.w += a3v.COMP * wv.w; }

__global__ __launch_bounds__(256) void k_mlp2(const float* __restrict__ a2,
        const float* __restrict__ W2, const float* __restrict__ b2,
        float* __restrict__ out, int n){
    __shared__ float w[128 * 128];   // 64 KB
    for (int i = threadIdx.x; i < 128 * 128; i += 256) w[i] = W2[i];
    __syncthreads();
    int c4 = (threadIdx.x & 31) * 4;
    int r0 = blockIdx.x * 32 + (threadIdx.x >> 5) * 4;
    float4 bias = *(const float4*)(b2 + c4);
    float4 acc0 = bias, acc1 = bias, acc2 = bias, acc3 = bias;
    const float* h0 = a2 + (size_t)(r0 + 0) * 128;
    const float* h1 = a2 + (size_t)(r0 + 1) * 128;
    const float* h2 = a2 + (size_t)(r0 + 2) * 128;
    const float* h3 = a2 + (size_t)(r0 + 3) * 128;
    bool g0 = r0 + 0 < n, g1 = r0 + 1 < n, g2 = r0 + 2 < n, g3 = r0 + 3 < n;
    const float4 z = make_float4(0.f, 0.f, 0.f, 0.f);
    for (int k = 0; k < 128; k += 4){
        float4 a0  = g0 ? *(const float4*)(h0 + k) : z;
        float4 a1v = g1 ? *(const float4*)(h1 + k) : z;
        float4 a2v = g2 ? *(const float4*)(h2 + k) : z;
        float4 a3v = g3 ? *(const float4*)(h3 + k) : z;
        MLP2_STEP(0, x)
        MLP2_STEP(1, y)
        MLP2_STEP(2, z)
        MLP2_STEP(3, w)
    }
    if (g0) *(float4*)(out + (size_t)(r0 + 0) * 128 + c4) = acc0;
    if (g1) *(float4*)(out + (size_t)(r0 + 1) * 128 + c4) = acc1;
    if (g2) *(float4*)(out + (size_t)(r0 + 2) * 128 + c4) = acc2;
    if (g3) *(float4*)(out + (size_t)(r0 + 3) * 128 + c4) = acc3;
}

extern "C" void kernel_launch(void* const* d_in, const int* in_sizes, int n_in,
                              void* d_out, int out_size, void* d_ws, size_t ws_size,
                              hipStream_t stream){
    const int*   x    = (const int*)d_in[0];
    const int*   ei   = (const int*)d_in[1];
    const float* emb  = (const float*)d_in[2];
    const float* W1   = (const float*)d_in[3];
    const float* b1   = (const float*)d_in[4];
    const float* W2   = (const float*)d_in[5];
    const float* b2   = (const float*)d_in[6];
    const int N = in_sizes[0];
    const int E = in_sizes[1] / 2;
    const int* srcv = ei;
    const int* dstv = ei + E;
    float* out = (float*)d_out;

    char* p = (char*)d_ws;
    auto alloc = [&](size_t bytes) -> char* {
        char* r = p; p += (bytes + 255) & ~(size_t)255; return r;
    };
    int nb = cdiv(N, 256);
    int*   ecount  = (int*)  alloc((size_t)N * 4);
    int*   offsets = (int*)  alloc((size_t)N * 4);
    int*   cursor  = (int*)  alloc((size_t)N * 4);
    int*   bsum    = (int*)  alloc((size_t)nb * 4);
    float* dinv    = (float*)alloc((size_t)N * 4);
    int*   csr     = (int*)  alloc((size_t)E * 4);
    float* es      = (float*)alloc((size_t)N * 32 * 4);
    float* a1      = (float*)alloc((size_t)N * 32 * 4);
    float* hs      = (float*)alloc((size_t)N * 128 * 4);
    float* a2      = (float*)alloc((size_t)N * 128 * 4);
    (void)ws_size; (void)n_in; (void)out_size;

    const int npp = cdiv(N, 8);   // nodes per partition (8 XCD-aligned partitions)

    // --- CSR build ---
    k_zero_i32<<<cdiv(N, 256), 256, 0, stream>>>(ecount, N);
    k_count   <<<1024, 256, 0, stream>>>(dstv, E, ecount, npp);
    k_dinv    <<<cdiv(N, 256), 256, 0, stream>>>(ecount, dinv, N);
    k_scanA   <<<nb, 256, 0, stream>>>(ecount, N, bsum);
    k_scanB   <<<1, 256, 0, stream>>>(bsum, nb);
    k_scanC   <<<nb, 256, 0, stream>>>(ecount, N, bsum, offsets, cursor);
    k_fill    <<<1024, 256, 0, stream>>>(srcv, dstv, E, cursor, csr, npp);

    // --- layer 1: scale -> agg(32) -> GEMM+relu (+dinv pre-scale for layer 2) ---
    k_scale <<<cdiv(N * 32, 256), 256, 0, stream>>>(emb, x, dinv, es, N);
    k_agg32 <<<cdiv(N, 8), 256, 0, stream>>>(es, offsets, ecount, csr, dinv, a1, N);
    k_mlp1  <<<cdiv(N, 8), 256, 0, stream>>>(a1, W1, b1, dinv, hs, N);

    // --- layer 2: agg(128) -> GEMM+bias -> out ---
    k_agg128<<<cdiv(N, 8), 256, 0, stream>>>(hs, offsets, ecount, csr, dinv, a2, N);
    k_mlp2  <<<cdiv(N, 32), 256, 0, stream>>>(a2, W2, b2, out, N);
}

// Round 4
// 405.563 us; speedup vs baseline: 1.7061x; 1.1518x over previous
//
#include <hip/hip_runtime.h>

// GCN: agg-before-GEMM on both layers (A(hW) = (Ah)W).
//   es  = bf16( dinv[i] * emb[x[i]] )               (N x 32, 64 B/row -> 3.2 MB, L2-resident)
//   a1  = dinv[i] * (es[i] + sum_{e:dst=i} es[src]) (gather, fp32 accum)
//   hs  = bf16( dinv[i] * relu(a1 @ W1 + b1) )      (N x 128, 256 B/row -> 12.8 MB)
//   a2  = dinv[i] * (hs[i] + sum hs[src])           (gather, fp32 accum)
//   out = a2 @ W2 + b2
// bf16 tables halve gather fabric traffic (R3: k_agg128 FETCH 360 MB @3.3 TB/s was
// the wall). CSR build keeps the XCD-aligned dst-range partitioning from R2.

static inline int cdiv(int a, int b){ return (a + b - 1) / b; }

__device__ __forceinline__ unsigned short f2bf(float f){
    unsigned int u = __float_as_uint(f);
    u += 0x7fffu + ((u >> 16) & 1u);          // round-to-nearest-even
    return (unsigned short)(u >> 16);
}
__device__ __forceinline__ float bf2f(unsigned short b){
    return __uint_as_float(((unsigned int)b) << 16);
}

__global__ void k_zero_i32(int* __restrict__ p, int n){
    int i = blockIdx.x * blockDim.x + threadIdx.x;
    if (i < n) p[i] = 0;
}

// Partitioned count: partition = blockIdx%8 handles dst in [lo,hi).
__global__ __launch_bounds__(256) void k_count(const int* __restrict__ dst, int E,
                                               int* __restrict__ ecount, int npp){
    int part = blockIdx.x & 7;
    int sub  = blockIdx.x >> 3;
    int nsub = gridDim.x >> 3;
    int lo = part * npp, hi = lo + npp;
    for (int e = sub * 256 + threadIdx.x; e < E; e += nsub * 256){
        int d = dst[e];
        if (d >= lo && d < hi) atomicAdd(&ecount[d], 1);
    }
}

__global__ void k_dinv(const int* __restrict__ ecount, float* __restrict__ dinv, int n){
    int i = blockIdx.x * blockDim.x + threadIdx.x;
    if (i < n) dinv[i] = rsqrtf((float)ecount[i] + 1.0f);  // +1 self-loop
}

__global__ void k_scanA(const int* __restrict__ ecount, int n, int* __restrict__ bsum){
    __shared__ int s[256];
    int t = threadIdx.x;
    int i = blockIdx.x * 256 + t;
    s[t] = (i < n) ? ecount[i] : 0;
    __syncthreads();
    for (int d = 128; d > 0; d >>= 1){
        if (t < d) s[t] += s[t + d];
        __syncthreads();
    }
    if (t == 0) bsum[blockIdx.x] = s[0];
}

__global__ void k_scanB(int* __restrict__ bsum, int nb){
    __shared__ int s[256];
    int t = threadIdx.x;
    s[t] = (t < nb) ? bsum[t] : 0;
    __syncthreads();
    if (t == 0){
        int run = 0;
        for (int b = 0; b < nb; b++){ int v = s[b]; s[b] = run; run += v; }
    }
    __syncthreads();
    if (t < nb) bsum[t] = s[t];
}

__global__ void k_scanC(const int* __restrict__ ecount, int n, const int* __restrict__ bsum,
                        int* __restrict__ offsets, int* __restrict__ cursor){
    __shared__ int s[256];
    int t = threadIdx.x;
    int i = blockIdx.x * 256 + t;
    int v = (i < n) ? ecount[i] : 0;
    s[t] = v;
    __syncthreads();
    for (int d = 1; d < 256; d <<= 1){
        int x = (t >= d) ? s[t - d] : 0;
        __syncthreads();
        s[t] += x;
        __syncthreads();
    }
    if (i < n){
        int off = bsum[blockIdx.x] + s[t] - v;
        offsets[i] = off;
        cursor[i]  = off;
    }
}

// Partitioned fill: same partition scheme as k_count.
__global__ __launch_bounds__(256) void k_fill(const int* __restrict__ src,
        const int* __restrict__ dst, int E, int* __restrict__ cursor,
        int* __restrict__ csr_src, int npp){
    int part = blockIdx.x & 7;
    int sub  = blockIdx.x >> 3;
    int nsub = gridDim.x >> 3;
    int lo = part * npp, hi = lo + npp;
    for (int e = sub * 256 + threadIdx.x; e < E; e += nsub * 256){
        int d = dst[e];
        if (d >= lo && d < hi){
            int pos = atomicAdd(&cursor[d], 1);
            csr_src[pos] = src[e];
        }
    }
}

// es[i][c] = bf16( emb[x[i]][c] * dinv[i] )
__global__ void k_scale(const float* __restrict__ emb, const int* __restrict__ x,
                        const float* __restrict__ dinv, unsigned short* __restrict__ es, int n){
    int idx = blockIdx.x * blockDim.x + threadIdx.x;
    if (idx >= n * 32) return;
    int i = idx >> 5;
    int c = idx & 31;
    es[idx] = f2bf(emb[(size_t)x[i] * 32 + c] * dinv[i]);
}

// a1[i] = dinv[i] * (es[i] + sum es[src]) ; 32 lanes/node, bf16 loads, unroll 8.
__global__ __launch_bounds__(256) void k_agg32(const unsigned short* __restrict__ es,
        const int* __restrict__ offsets, const int* __restrict__ ecount,
        const int* __restrict__ csr, const float* __restrict__ dinv,
        float* __restrict__ a1, int n){
    int node = blockIdx.x * 8 + (threadIdx.x >> 5);
    int lane = threadIdx.x & 31;
    if (node >= n) return;
    int off = offsets[node], cnt = ecount[node];
    float s0 = bf2f(es[(size_t)node * 32 + lane]);   // self-loop term
    float s1 = 0.f;
    int e = 0;
    for (; e + 8 <= cnt; e += 8){
        int i0 = csr[off + e + 0], i1 = csr[off + e + 1];
        int i2 = csr[off + e + 2], i3 = csr[off + e + 3];
        int i4 = csr[off + e + 4], i5 = csr[off + e + 5];
        int i6 = csr[off + e + 6], i7 = csr[off + e + 7];
        unsigned short v0 = es[(size_t)i0 * 32 + lane];
        unsigned short v1 = es[(size_t)i1 * 32 + lane];
        unsigned short v2 = es[(size_t)i2 * 32 + lane];
        unsigned short v3 = es[(size_t)i3 * 32 + lane];
        unsigned short v4 = es[(size_t)i4 * 32 + lane];
        unsigned short v5 = es[(size_t)i5 * 32 + lane];
        unsigned short v6 = es[(size_t)i6 * 32 + lane];
        unsigned short v7 = es[(size_t)i7 * 32 + lane];
        s0 += bf2f(v0) + bf2f(v2) + bf2f(v4) + bf2f(v6);
        s1 += bf2f(v1) + bf2f(v3) + bf2f(v5) + bf2f(v7);
    }
    for (; e < cnt; e++) s0 += bf2f(es[(size_t)csr[off + e] * 32 + lane]);
    a1[(size_t)node * 32 + lane] = dinv[node] * (s0 + s1);
}

// hs[i] = bf16( dinv[i] * relu(a1[i] @ W1 + b1) ) ; W1 in LDS, K=32 unrolled.
__global__ __launch_bounds__(256) void k_mlp1(const float* __restrict__ a1,
        const float* __restrict__ W1, const float* __restrict__ b1,
        const float* __restrict__ dinv, unsigned short* __restrict__ hs, int n){
    __shared__ float w[32 * 128];
    for (int i = threadIdx.x; i < 32 * 128; i += 256) w[i] = W1[i];
    __syncthreads();
    int c4  = (threadIdx.x & 31) * 4;
    int row = blockIdx.x * 8 + (threadIdx.x >> 5);
    if (row >= n) return;
    const float4* ar = (const float4*)(a1 + (size_t)row * 32);
    float4 acc = *(const float4*)(b1 + c4);
    #pragma unroll
    for (int k4 = 0; k4 < 8; k4++){
        float4 av = ar[k4];
        float4 w0 = *(const float4*)&w[(k4 * 4 + 0) * 128 + c4];
        float4 w1 = *(const float4*)&w[(k4 * 4 + 1) * 128 + c4];
        float4 w2 = *(const float4*)&w[(k4 * 4 + 2) * 128 + c4];
        float4 w3 = *(const float4*)&w[(k4 * 4 + 3) * 128 + c4];
        acc.x += av.x * w0.x + av.y * w1.x + av.z * w2.x + av.w * w3.x;
        acc.y += av.x * w0.y + av.y * w1.y + av.z * w2.y + av.w * w3.y;
        acc.z += av.x * w0.z + av.y * w1.z + av.z * w2.z + av.w * w3.z;
        acc.w += av.x * w0.w + av.y * w1.w + av.z * w2.w + av.w * w3.w;
    }
    float dv = dinv[row];
    ushort4 o;
    o.x = f2bf(dv * fmaxf(acc.x, 0.f));
    o.y = f2bf(dv * fmaxf(acc.y, 0.f));
    o.z = f2bf(dv * fmaxf(acc.z, 0.f));
    o.w = f2bf(dv * fmaxf(acc.w, 0.f));
    *(ushort4*)(hs + (size_t)row * 128 + c4) = o;
}

// a2[i] = dinv[i] * (hs[i] + sum hs[src]) ; 32 lanes/node, ushort4 (4xbf16)/lane, unroll 8.
__global__ __launch_bounds__(256) void k_agg128(const unsigned short* __restrict__ hs,
        const int* __restrict__ offsets, const int* __restrict__ ecount,
        const int* __restrict__ csr, const float* __restrict__ dinv,
        float* __restrict__ a2, int n){
    int node = blockIdx.x * 8 + (threadIdx.x >> 5);
    int lane = threadIdx.x & 31;
    if (node >= n) return;
    int off = offsets[node], cnt = ecount[node];
    int c4 = lane * 4;
    ushort4 sv = *(const ushort4*)(hs + (size_t)node * 128 + c4);   // self-loop
    float ax0 = bf2f(sv.x), ax1 = 0.f;
    float ay0 = bf2f(sv.y), ay1 = 0.f;
    float az0 = bf2f(sv.z), az1 = 0.f;
    float aw0 = bf2f(sv.w), aw1 = 0.f;
    int e = 0;
    for (; e + 8 <= cnt; e += 8){
        int i0 = csr[off + e + 0], i1 = csr[off + e + 1];
        int i2 = csr[off + e + 2], i3 = csr[off + e + 3];
        int i4 = csr[off + e + 4], i5 = csr[off + e + 5];
        int i6 = csr[off + e + 6], i7 = csr[off + e + 7];
        ushort4 v0 = *(const ushort4*)(hs + (size_t)i0 * 128 + c4);
        ushort4 v1 = *(const ushort4*)(hs + (size_t)i1 * 128 + c4);
        ushort4 v2 = *(const ushort4*)(hs + (size_t)i2 * 128 + c4);
        ushort4 v3 = *(const ushort4*)(hs + (size_t)i3 * 128 + c4);
        ushort4 v4 = *(const ushort4*)(hs + (size_t)i4 * 128 + c4);
        ushort4 v5 = *(const ushort4*)(hs + (size_t)i5 * 128 + c4);
        ushort4 v6 = *(const ushort4*)(hs + (size_t)i6 * 128 + c4);
        ushort4 v7 = *(const ushort4*)(hs + (size_t)i7 * 128 + c4);
        ax0 += bf2f(v0.x) + bf2f(v2.x) + bf2f(v4.x) + bf2f(v6.x);
        ax1 += bf2f(v1.x) + bf2f(v3.x) + bf2f(v5.x) + bf2f(v7.x);
        ay0 += bf2f(v0.y) + bf2f(v2.y) + bf2f(v4.y) + bf2f(v6.y);
        ay1 += bf2f(v1.y) + bf2f(v3.y) + bf2f(v5.y) + bf2f(v7.y);
        az0 += bf2f(v0.z) + bf2f(v2.z) + bf2f(v4.z) + bf2f(v6.z);
        az1 += bf2f(v1.z) + bf2f(v3.z) + bf2f(v5.z) + bf2f(v7.z);
        aw0 += bf2f(v0.w) + bf2f(v2.w) + bf2f(v4.w) + bf2f(v6.w);
        aw1 += bf2f(v1.w) + bf2f(v3.w) + bf2f(v5.w) + bf2f(v7.w);
    }
    for (; e < cnt; e++){
        ushort4 v = *(const ushort4*)(hs + (size_t)csr[off + e] * 128 + c4);
        ax0 += bf2f(v.x); ay0 += bf2f(v.y); az0 += bf2f(v.z); aw0 += bf2f(v.w);
    }
    float dv = dinv[node];
    float4 r;
    r.x = dv * (ax0 + ax1); r.y = dv * (ay0 + ay1);
    r.z = dv * (az0 + az1); r.w = dv * (aw0 + aw1);
    *(float4*)(a2 + (size_t)node * 128 + c4) = r;
}

// out[i] = a2[i] @ W2 + b2 ; W2 in LDS (64 KB), 4 rows x 4 cols per thread.
#define MLP2_STEP(KK, COMP) {                                        \
    float4 wv = *(const float4*)&w[(k + KK) * 128 + c4];             \
    acc0.x += a0.COMP * wv.x; acc0.y += a0.COMP * wv.y;              \
    acc0.z += a0.COMP * wv.z; acc0.w += a0.COMP * wv.w;              \
    acc1.x += a1v.COMP * wv.x; acc1.y += a1v.COMP * wv.y;            \
    acc1.z += a1v.COMP * wv.z; acc1.w += a1v.COMP * wv.w;            \
    acc2.x += a2v.COMP * wv.x; acc2.y += a2v.COMP * wv.y;            \
    acc2.z += a2v.COMP * wv.z; acc2.w += a2v.COMP * wv.w;            \
    acc3.x += a3v.COMP * wv.x; acc3.y += a3v.COMP * wv.y;            \
    acc3.z += a3v.COMP * wv.z; acc3.w += a3v.COMP * wv.w; }

__global__ __launch_bounds__(256) void k_mlp2(const float* __restrict__ a2,
        const float* __restrict__ W2, const float* __restrict__ b2,
        float* __restrict__ out, int n){
    __shared__ float w[128 * 128];   // 64 KB
    for (int i = threadIdx.x; i < 128 * 128; i += 256) w[i] = W2[i];
    __syncthreads();
    int c4 = (threadIdx.x & 31) * 4;
    int r0 = blockIdx.x * 32 + (threadIdx.x >> 5) * 4;
    float4 bias = *(const float4*)(b2 + c4);
    float4 acc0 = bias, acc1 = bias, acc2 = bias, acc3 = bias;
    const float* h0 = a2 + (size_t)(r0 + 0) * 128;
    const float* h1 = a2 + (size_t)(r0 + 1) * 128;
    const float* h2 = a2 + (size_t)(r0 + 2) * 128;
    const float* h3 = a2 + (size_t)(r0 + 3) * 128;
    bool g0 = r0 + 0 < n, g1 = r0 + 1 < n, g2 = r0 + 2 < n, g3 = r0 + 3 < n;
    const float4 z = make_float4(0.f, 0.f, 0.f, 0.f);
    for (int k = 0; k < 128; k += 4){
        float4 a0  = g0 ? *(const float4*)(h0 + k) : z;
        float4 a1v = g1 ? *(const float4*)(h1 + k) : z;
        float4 a2v = g2 ? *(const float4*)(h2 + k) : z;
        float4 a3v = g3 ? *(const float4*)(h3 + k) : z;
        MLP2_STEP(0, x)
        MLP2_STEP(1, y)
        MLP2_STEP(2, z)
        MLP2_STEP(3, w)
    }
    if (g0) *(float4*)(out + (size_t)(r0 + 0) * 128 + c4) = acc0;
    if (g1) *(float4*)(out + (size_t)(r0 + 1) * 128 + c4) = acc1;
    if (g2) *(float4*)(out + (size_t)(r0 + 2) * 128 + c4) = acc2;
    if (g3) *(float4*)(out + (size_t)(r0 + 3) * 128 + c4) = acc3;
}

extern "C" void kernel_launch(void* const* d_in, const int* in_sizes, int n_in,
                              void* d_out, int out_size, void* d_ws, size_t ws_size,
                              hipStream_t stream){
    const int*   x    = (const int*)d_in[0];
    const int*   ei   = (const int*)d_in[1];
    const float* emb  = (const float*)d_in[2];
    const float* W1   = (const float*)d_in[3];
    const float* b1   = (const float*)d_in[4];
    const float* W2   = (const float*)d_in[5];
    const float* b2   = (const float*)d_in[6];
    const int N = in_sizes[0];
    const int E = in_sizes[1] / 2;
    const int* srcv = ei;
    const int* dstv = ei + E;
    float* out = (float*)d_out;

    char* p = (char*)d_ws;
    auto alloc = [&](size_t bytes) -> char* {
        char* r = p; p += (bytes + 255) & ~(size_t)255; return r;
    };
    int nb = cdiv(N, 256);
    int*            ecount  = (int*)           alloc((size_t)N * 4);
    int*            offsets = (int*)           alloc((size_t)N * 4);
    int*            cursor  = (int*)           alloc((size_t)N * 4);
    int*            bsum    = (int*)           alloc((size_t)nb * 4);
    float*          dinv    = (float*)         alloc((size_t)N * 4);
    int*            csr     = (int*)           alloc((size_t)E * 4);
    unsigned short* es      = (unsigned short*)alloc((size_t)N * 32 * 2);
    float*          a1      = (float*)         alloc((size_t)N * 32 * 4);
    unsigned short* hs      = (unsigned short*)alloc((size_t)N * 128 * 2);
    float*          a2      = (float*)         alloc((size_t)N * 128 * 4);
    (void)ws_size; (void)n_in; (void)out_size;

    const int npp = cdiv(N, 8);   // nodes per partition (8 XCD-aligned partitions)

    // --- CSR build ---
    k_zero_i32<<<cdiv(N, 256), 256, 0, stream>>>(ecount, N);
    k_count   <<<1024, 256, 0, stream>>>(dstv, E, ecount, npp);
    k_dinv    <<<cdiv(N, 256), 256, 0, stream>>>(ecount, dinv, N);
    k_scanA   <<<nb, 256, 0, stream>>>(ecount, N, bsum);
    k_scanB   <<<1, 256, 0, stream>>>(bsum, nb);
    k_scanC   <<<nb, 256, 0, stream>>>(ecount, N, bsum, offsets, cursor);
    k_fill    <<<1024, 256, 0, stream>>>(srcv, dstv, E, cursor, csr, npp);

    // --- layer 1: scale -> agg(32) -> GEMM+relu (+dinv pre-scale for layer 2) ---
    k_scale <<<cdiv(N * 32, 256), 256, 0, stream>>>(emb, x, dinv, es, N);
    k_agg32 <<<cdiv(N, 8), 256, 0, stream>>>(es, offsets, ecount, csr, dinv, a1, N);
    k_mlp1  <<<cdiv(N, 8), 256, 0, stream>>>(a1, W1, b1, dinv, hs, N);

    // --- layer 2: agg(128) -> GEMM+bias -> out ---
    k_agg128<<<cdiv(N, 8), 256, 0, stream>>>(hs, offsets, ecount, csr, dinv, a2, N);
    k_mlp2  <<<cdiv(N, 32), 256, 0, stream>>>(a2, W2, b2, out, N);
}